// Round 6
// baseline (614.832 us; speedup 1.0000x reference)
//
#include <hip/hip_runtime.h>

// GCN 2-layer forward, f32 — feature-sliced CSR gather.
// A_hat(X@W1) = (A_hat X)@W1; layer 2 is scalar aggregation of s = h@W2.
// Slice trick: 8 feature-slices of 8 floats; slice s -> XCD s via blockIdx&7,
// so each XCD's gather working set is 3.2 MB (fits 4 MB L2) instead of 25.6 MB.

#define NNODES 100000
#define INF 64
#define HID 128
#define NPB 16        // nodes per block (16 waves x 1 node)
#define REC_CAP 1024  // LDS record capacity for slice kernel
#define REC_CAP_F 1536

typedef unsigned long long u64;

__global__ void k_hist(const int* __restrict__ dst, int* __restrict__ cnt, int nE) {
    int e = blockIdx.x * blockDim.x + threadIdx.x;
    if (e < nE) {
        int d = dst[e];
        if ((unsigned)d < (unsigned)NNODES) atomicAdd(&cnt[d], 1);
    }
}

__global__ void k_scan1(const int* __restrict__ cnt, int* __restrict__ excl,
                        int* __restrict__ bsums, int n) {
    __shared__ int tmp[256];
    int tid = threadIdx.x;
    int base = blockIdx.x * 1024 + tid * 4;
    int v0 = (base + 0 < n) ? cnt[base + 0] : 0;
    int v1 = (base + 1 < n) ? cnt[base + 1] : 0;
    int v2 = (base + 2 < n) ? cnt[base + 2] : 0;
    int v3 = (base + 3 < n) ? cnt[base + 3] : 0;
    int t = v0 + v1 + v2 + v3;
    tmp[tid] = t;
    __syncthreads();
    for (int off = 1; off < 256; off <<= 1) {
        int u = (tid >= off) ? tmp[tid - off] : 0;
        __syncthreads();
        tmp[tid] += u;
        __syncthreads();
    }
    int ex = tmp[tid] - t;
    if (base + 0 < n) excl[base + 0] = ex;
    if (base + 1 < n) excl[base + 1] = ex + v0;
    if (base + 2 < n) excl[base + 2] = ex + v0 + v1;
    if (base + 3 < n) excl[base + 3] = ex + v0 + v1 + v2;
    if (tid == 255) bsums[blockIdx.x] = tmp[255];
}

__global__ void k_scan2(int* bsums, int nb) {
    __shared__ int tmp[256];
    int tid = threadIdx.x;
    int t = (tid < nb) ? bsums[tid] : 0;
    tmp[tid] = t;
    __syncthreads();
    for (int off = 1; off < 256; off <<= 1) {
        int u = (tid >= off) ? tmp[tid - off] : 0;
        __syncthreads();
        tmp[tid] += u;
        __syncthreads();
    }
    if (tid < nb) bsums[tid] = tmp[tid] - t;
}

__global__ void k_finalize(int* __restrict__ rowPtr, int* __restrict__ cursor,
                           const int* __restrict__ bsums, const int* __restrict__ counts,
                           float* __restrict__ dinv, int n, int E) {
    int i = blockIdx.x * blockDim.x + threadIdx.x;
    if (i < n) {
        int v = rowPtr[i] + bsums[i >> 10];
        rowPtr[i] = v;
        cursor[i] = v;
        dinv[i] = rsqrtf((float)(counts[i] + 1));  // +1 self loop
    }
    if (i == 0) rowPtr[n] = E;
}

__global__ void k_fill(const int* __restrict__ srcA, const int* __restrict__ dstA,
                       const float* __restrict__ dinv, int* __restrict__ cursor,
                       u64* __restrict__ eSW, int nE) {
    int e = blockIdx.x * blockDim.x + threadIdx.x;
    if (e < nE) {
        int s = srcA[e];
        int d = dstA[e];
        if ((unsigned)s < (unsigned)NNODES && (unsigned)d < (unsigned)NNODES) {
            int pos = atomicAdd(&cursor[d], 1);
            eSW[pos] = (u64)(unsigned)s | ((u64)__float_as_uint(dinv[s]) << 32);
        }
    }
}

// X[node][64] -> Xt[s][node][8]  (slice-major, 32 B per node per slice)
__global__ void k_transpose(const float4* __restrict__ X4, float4* __restrict__ Xt4, int n) {
    int t = blockIdx.x * blockDim.x + threadIdx.x;  // t = s*(n*2) + node*2 + c
    if (t >= n * 16) return;
    int c = t & 1;
    int rest = t >> 1;
    int node = rest % n;
    int s = rest / n;
    Xt4[t] = X4[(size_t)node * 16 + s * 2 + c];  // write coalesced
}

// Slice aggregation: block (chunk, s=blockIdx&7). 16 waves x 1 node.
// Lane pair (l>>1) walks edges stride-32; comp c=l&1 covers float4 half of slice.
// agg[node][s*8 .. s*8+8) = dD * (sum_e w_e * Xt[s][src] + dD * Xt[s][node])
__global__ __launch_bounds__(1024) void k_agg_slice(const float4* __restrict__ Xt4,
                                                    const int* __restrict__ rowPtr,
                                                    const u64* __restrict__ eSW,
                                                    const float* __restrict__ dinv,
                                                    float4* __restrict__ agg4, int n) {
    __shared__ u64 recs[REC_CAP];  // 8 KB
    int s = blockIdx.x & 7;
    int chunk = blockIdx.x >> 3;
    int n0 = chunk * NPB;
    int nEndNode = min(n0 + NPB, n);
    int rBeg = rowPtr[n0];
    int rEnd = rowPtr[nEndNode];
    int total = min(rEnd - rBeg, REC_CAP);
    for (int i = threadIdx.x; i < total; i += blockDim.x)
        recs[i] = eSW[rBeg + i];
    __syncthreads();

    int node = n0 + (threadIdx.x >> 6);
    if (node >= n) return;
    int lane = threadIdx.x & 63;
    int pair = lane >> 1;
    int c = lane & 1;
    int beg = rowPtr[node];
    int end = rowPtr[node + 1];
    const float4* base = Xt4 + (size_t)s * (n * 2);

    float4 acc = {0.0f, 0.0f, 0.0f, 0.0f};
    for (int j = beg + pair; j < end; j += 32) {
        int jj = j - rBeg;
        u64 p = (jj < REC_CAP) ? recs[jj] : eSW[j];
        int src = (int)(unsigned)p;
        float w = __uint_as_float((unsigned)(p >> 32));
        float4 x = base[(size_t)src * 2 + c];
        acc.x = fmaf(w, x.x, acc.x); acc.y = fmaf(w, x.y, acc.y);
        acc.z = fmaf(w, x.z, acc.z); acc.w = fmaf(w, x.w, acc.w);
    }
#pragma unroll
    for (int off = 2; off <= 32; off <<= 1) {
        acc.x += __shfl_xor(acc.x, off, 64); acc.y += __shfl_xor(acc.y, off, 64);
        acc.z += __shfl_xor(acc.z, off, 64); acc.w += __shfl_xor(acc.w, off, 64);
    }
    if (lane < 2) {
        float dD = dinv[node];
        float4 xs = base[(size_t)node * 2 + c];
        acc.x = dD * fmaf(dD, xs.x, acc.x);
        acc.y = dD * fmaf(dD, xs.y, acc.y);
        acc.z = dD * fmaf(dD, xs.z, acc.z);
        acc.w = dD * fmaf(dD, xs.w, acc.w);
        agg4[(size_t)node * 16 + s * 2 + c] = acc;
    }
}

// wave per node, streaming agg read: sv[node] = dot(relu(agg@W1 + b1), W2)
__global__ __launch_bounds__(1024) void k_mlp(const float4* __restrict__ agg4,
                                              const float* __restrict__ W1,
                                              const float* __restrict__ b1,
                                              const float* __restrict__ W2,
                                              float* __restrict__ sv, int n) {
    __shared__ float W1s[INF * HID];  // 32 KB
    __shared__ float b1s[HID];
    __shared__ float W2s[HID];
    for (int i = threadIdx.x; i < INF * HID / 4; i += blockDim.x)
        ((float4*)W1s)[i] = ((const float4*)W1)[i];
    if (threadIdx.x < HID) {
        b1s[threadIdx.x] = b1[threadIdx.x];
        W2s[threadIdx.x] = W2[threadIdx.x];
    }
    __syncthreads();

    int lane = threadIdx.x & 63;
    int r = lane & 15;
    int q = lane >> 4;
    int node = (blockIdx.x * blockDim.x + threadIdx.x) >> 6;
    if (node >= n) return;

    float4 av = {0.0f, 0.0f, 0.0f, 0.0f};
    if (q == 0) av = agg4[(size_t)node * 16 + r];  // lanes 0-15 hold the row

    float a0 = 0.0f, a1 = 0.0f;
#pragma unroll
    for (int k = 0; k < INF; ++k) {
        float srcv = ((k & 3) == 0) ? av.x : ((k & 3) == 1) ? av.y : ((k & 3) == 2) ? av.z : av.w;
        float xk = __shfl(srcv, k >> 2, 64);
        a0 = fmaf(xk, W1s[k * HID + lane], a0);
        a1 = fmaf(xk, W1s[k * HID + 64 + lane], a1);
    }
    float h0 = fmaxf(a0 + b1s[lane], 0.0f);
    float h1 = fmaxf(a1 + b1s[64 + lane], 0.0f);
    float p = h0 * W2s[lane] + h1 * W2s[64 + lane];
#pragma unroll
    for (int off = 32; off > 0; off >>= 1) p += __shfl_xor(p, off, 64);
    if (lane == 0) sv[node] = p;
}

// Fallback (R5): fused gather+MLP when ws too small for the sliced path.
__global__ __launch_bounds__(1024) void k_agg_mlp_fused(const float4* __restrict__ X4,
                                                        const int* __restrict__ rowPtr,
                                                        const u64* __restrict__ eSW,
                                                        const float* __restrict__ dinv,
                                                        const float* __restrict__ W1,
                                                        const float* __restrict__ b1,
                                                        const float* __restrict__ W2,
                                                        float* __restrict__ sv, int n) {
    __shared__ float W1s[INF * HID];
    __shared__ float b1s[HID];
    __shared__ float W2s[HID];
    __shared__ u64 recs[REC_CAP_F];
    for (int i = threadIdx.x; i < INF * HID / 4; i += blockDim.x)
        ((float4*)W1s)[i] = ((const float4*)W1)[i];
    if (threadIdx.x < HID) {
        b1s[threadIdx.x] = b1[threadIdx.x];
        W2s[threadIdx.x] = W2[threadIdx.x];
    }
    int n0 = blockIdx.x * NPB;
    int nEndNode = min(n0 + NPB, n);
    int rBeg = rowPtr[n0];
    int rEnd = rowPtr[nEndNode];
    int total = min(rEnd - rBeg, REC_CAP_F);
    for (int i = threadIdx.x; i < total; i += blockDim.x)
        recs[i] = eSW[rBeg + i];
    __syncthreads();

    int lane = threadIdx.x & 63;
    int r = lane & 15;
    int q = lane >> 4;
    int node = n0 + (threadIdx.x >> 6);
    if (node >= n) return;
    int beg = rowPtr[node];
    int end = rowPtr[node + 1];
    float dD = dinv[node];
    float4 acc = {0.0f, 0.0f, 0.0f, 0.0f};
    if (q == 0) {
        float4 xn = X4[(size_t)node * 16 + r];
        acc.x = dD * xn.x; acc.y = dD * xn.y; acc.z = dD * xn.z; acc.w = dD * xn.w;
    }
    int lbeg = beg - rBeg + q;
    int lend = end - rBeg;
#pragma unroll 2
    for (int jj = lbeg; jj < lend; jj += 4) {
        u64 p = (jj < REC_CAP_F) ? recs[jj] : eSW[rBeg + jj];
        int sI = (int)(unsigned)p;
        float w = __uint_as_float((unsigned)(p >> 32));
        float4 x = X4[(size_t)sI * 16 + r];
        acc.x = fmaf(w, x.x, acc.x); acc.y = fmaf(w, x.y, acc.y);
        acc.z = fmaf(w, x.z, acc.z); acc.w = fmaf(w, x.w, acc.w);
    }
    acc.x += __shfl_xor(acc.x, 16, 64); acc.y += __shfl_xor(acc.y, 16, 64);
    acc.z += __shfl_xor(acc.z, 16, 64); acc.w += __shfl_xor(acc.w, 16, 64);
    acc.x += __shfl_xor(acc.x, 32, 64); acc.y += __shfl_xor(acc.y, 32, 64);
    acc.z += __shfl_xor(acc.z, 32, 64); acc.w += __shfl_xor(acc.w, 32, 64);
    float av0 = dD * acc.x, av1 = dD * acc.y, av2 = dD * acc.z, av3 = dD * acc.w;
    float a0 = 0.0f, a1 = 0.0f;
#pragma unroll
    for (int k = 0; k < INF; ++k) {
        float srcv = ((k & 3) == 0) ? av0 : ((k & 3) == 1) ? av1 : ((k & 3) == 2) ? av2 : av3;
        float xk = __shfl(srcv, k >> 2, 64);
        a0 = fmaf(xk, W1s[k * HID + lane], a0);
        a1 = fmaf(xk, W1s[k * HID + 64 + lane], a1);
    }
    float h0 = fmaxf(a0 + b1s[lane], 0.0f);
    float h1 = fmaxf(a1 + b1s[64 + lane], 0.0f);
    float p = h0 * W2s[lane] + h1 * W2s[64 + lane];
#pragma unroll
    for (int off = 32; off > 0; off >>= 1) p += __shfl_xor(p, off, 64);
    if (lane == 0) sv[node] = p;
}

// 4 nodes per wave (16-lane segments)
__global__ __launch_bounds__(256) void k_out(const int* __restrict__ rowPtr,
                                             const u64* __restrict__ eSW,
                                             const float* __restrict__ dinv,
                                             const float* __restrict__ sv,
                                             const float* __restrict__ b2,
                                             float* __restrict__ out, int n) {
    int t = blockIdx.x * blockDim.x + threadIdx.x;
    int node = t >> 4;
    int r = t & 15;
    if (node >= n) return;
    int beg = rowPtr[node];
    int end = rowPtr[node + 1];
    float p = 0.0f;
    for (int j = beg + r; j < end; j += 16) {
        u64 pe = eSW[j];
        int s = (int)(unsigned)pe;
        float w = __uint_as_float((unsigned)(pe >> 32));
        p = fmaf(w, sv[s], p);
    }
    p += __shfl_xor(p, 1, 16);
    p += __shfl_xor(p, 2, 16);
    p += __shfl_xor(p, 4, 16);
    p += __shfl_xor(p, 8, 16);
    if (r == 0) {
        float dD = dinv[node];
        out[node] = fmaf(dD, p, fmaf(dD * dD, sv[node], b2[0]));
    }
}

extern "C" void kernel_launch(void* const* d_in, const int* in_sizes, int n_in,
                              void* d_out, int out_size, void* d_ws, size_t ws_size,
                              hipStream_t stream) {
    const float* X  = (const float*)d_in[0];
    const int*   ei = (const int*)d_in[1];   // int32 (jax x64 disabled)
    const float* W1 = (const float*)d_in[2];
    const float* b1 = (const float*)d_in[3];
    const float* W2 = (const float*)d_in[4];
    const float* b2 = (const float*)d_in[5];

    int N = in_sizes[0] / INF;  // 100000
    int E = in_sizes[1] / 2;    // 1600000
    const int* srcA = ei;
    const int* dstA = ei + E;

    // common workspace head
    u64*   eSW    = (u64*)d_ws;                       // E
    size_t featF  = (size_t)N * INF;                  // 6.4M floats
    float* Xt     = (float*)(eSW + E);                // N*64 (sliced path)
    float* agg    = Xt + featF;                       // N*64
    float* tail   = agg + featF;
    size_t needed = (size_t)E * 8 + featF * 4 * 2 + ((size_t)4 * N + 260) * 4 + 64;
    bool sliced = ws_size >= needed;
    if (!sliced) tail = (float*)(eSW + E);            // fallback: small tail only

    int*   counts = (int*)tail;             // N
    int*   rowPtr = counts + N;             // N+1
    int*   cursor = rowPtr + N + 1;         // N
    int*   bsums  = cursor + N;             // 256
    float* dinv   = (float*)(bsums + 256);  // N
    float* sv     = dinv + N;               // N
    float* out    = (float*)d_out;

    int nbN = (N + 255) / 256;
    int nbE = (E + 255) / 256;
    int nb1 = (N + 1023) / 1024;
    int nChunks = (N + NPB - 1) / NPB;

    hipMemsetAsync(counts, 0, (size_t)N * sizeof(int), stream);
    k_hist<<<nbE, 256, 0, stream>>>(dstA, counts, E);
    k_scan1<<<nb1, 256, 0, stream>>>(counts, rowPtr, bsums, N);
    k_scan2<<<1, 256, 0, stream>>>(bsums, nb1);
    k_finalize<<<nbN, 256, 0, stream>>>(rowPtr, cursor, bsums, counts, dinv, N, E);
    k_fill<<<nbE, 256, 0, stream>>>(srcA, dstA, dinv, cursor, eSW, E);

    if (sliced) {
        k_transpose<<<(N * 16 + 255) / 256, 256, 0, stream>>>((const float4*)X,
                                                              (float4*)Xt, N);
        k_agg_slice<<<nChunks * 8, 1024, 0, stream>>>((const float4*)Xt, rowPtr, eSW,
                                                      dinv, (float4*)agg, N);
        k_mlp<<<(N * 64 + 1023) / 1024, 1024, 0, stream>>>((const float4*)agg,
                                                           W1, b1, W2, sv, N);
    } else {
        k_agg_mlp_fused<<<nChunks, 1024, 0, stream>>>((const float4*)X, rowPtr, eSW,
                                                      dinv, W1, b1, W2, sv, N);
    }
    k_out<<<(N * 16 + 255) / 256, 256, 0, stream>>>(rowPtr, eSW, dinv, sv, b2, out, N);
}

// Round 7
// 340.017 us; speedup vs baseline: 1.8082x; 1.8082x over previous
//
#include <hip/hip_runtime.h>
#include <hip/hip_fp16.h>

// GCN 2-layer forward — CSR-gather with f16 pre-scaled features.
// Algebra: A_hat(X@W1) = (A_hat X)@W1; layer 2 is scalar aggregation of s=h@W2.
// Pre-scale Xs = dinv*X (f16, 128 B/row) => CSR records are src-only (4 B),
// agg[d] = dinv_d*(sum Xs[src] + Xs[d]); same trick for layer 2 via svs=dinv*sv.

#define NNODES 100000
#define INF 64
#define HID 128
#define NPB 16        // nodes per block (16 waves x 1 node)
#define REC_CAP 2048  // LDS record capacity (ints); mean block usage ~256

__global__ void k_hist(const int* __restrict__ dst, int* __restrict__ cnt, int nE) {
    int e = blockIdx.x * blockDim.x + threadIdx.x;
    if (e < nE) {
        int d = dst[e];
        if ((unsigned)d < (unsigned)NNODES) atomicAdd(&cnt[d], 1);
    }
}

__global__ void k_scan1(const int* __restrict__ cnt, int* __restrict__ excl,
                        int* __restrict__ bsums, int n) {
    __shared__ int tmp[256];
    int tid = threadIdx.x;
    int base = blockIdx.x * 1024 + tid * 4;
    int v0 = (base + 0 < n) ? cnt[base + 0] : 0;
    int v1 = (base + 1 < n) ? cnt[base + 1] : 0;
    int v2 = (base + 2 < n) ? cnt[base + 2] : 0;
    int v3 = (base + 3 < n) ? cnt[base + 3] : 0;
    int t = v0 + v1 + v2 + v3;
    tmp[tid] = t;
    __syncthreads();
    for (int off = 1; off < 256; off <<= 1) {
        int u = (tid >= off) ? tmp[tid - off] : 0;
        __syncthreads();
        tmp[tid] += u;
        __syncthreads();
    }
    int ex = tmp[tid] - t;
    if (base + 0 < n) excl[base + 0] = ex;
    if (base + 1 < n) excl[base + 1] = ex + v0;
    if (base + 2 < n) excl[base + 2] = ex + v0 + v1;
    if (base + 3 < n) excl[base + 3] = ex + v0 + v1 + v2;
    if (tid == 255) bsums[blockIdx.x] = tmp[255];
}

__global__ void k_scan2(int* bsums, int nb) {
    __shared__ int tmp[256];
    int tid = threadIdx.x;
    int t = (tid < nb) ? bsums[tid] : 0;
    tmp[tid] = t;
    __syncthreads();
    for (int off = 1; off < 256; off <<= 1) {
        int u = (tid >= off) ? tmp[tid - off] : 0;
        __syncthreads();
        tmp[tid] += u;
        __syncthreads();
    }
    if (tid < nb) bsums[tid] = tmp[tid] - t;
}

__global__ void k_finalize(int* __restrict__ rowPtr, int* __restrict__ cursor,
                           const int* __restrict__ bsums, const int* __restrict__ counts,
                           float* __restrict__ dinv, int n, int E) {
    int i = blockIdx.x * blockDim.x + threadIdx.x;
    if (i < n) {
        int v = rowPtr[i] + bsums[i >> 10];
        rowPtr[i] = v;
        cursor[i] = v;
        dinv[i] = rsqrtf((float)(counts[i] + 1));  // +1 self loop
    }
    if (i == 0) rowPtr[n] = E;
}

// Xs[node][64] (f16) = dinv[node] * X[node][64]; row = 8 x uint4 (128 B)
__global__ void k_prescale(const float4* __restrict__ X4, const float* __restrict__ dinv,
                           uint4* __restrict__ Xs4, int n) {
    int t = blockIdx.x * blockDim.x + threadIdx.x;
    if (t >= n * 8) return;
    int node = t >> 3;
    int r = t & 7;
    float dD = dinv[node];
    float4 a = X4[(size_t)node * 16 + r * 2];
    float4 b = X4[(size_t)node * 16 + r * 2 + 1];
    __half2 h0 = __float22half2_rn(make_float2(dD * a.x, dD * a.y));
    __half2 h1 = __float22half2_rn(make_float2(dD * a.z, dD * a.w));
    __half2 h2 = __float22half2_rn(make_float2(dD * b.x, dD * b.y));
    __half2 h3 = __float22half2_rn(make_float2(dD * b.z, dD * b.w));
    uint4 o;
    o.x = *(unsigned*)&h0; o.y = *(unsigned*)&h1;
    o.z = *(unsigned*)&h2; o.w = *(unsigned*)&h3;
    Xs4[t] = o;
}

// fill CSR with src-only 4B records
__global__ void k_fill(const int* __restrict__ srcA, const int* __restrict__ dstA,
                       int* __restrict__ cursor, int* __restrict__ eSrc, int nE) {
    int e = blockIdx.x * blockDim.x + threadIdx.x;
    if (e < nE) {
        int s = srcA[e];
        int d = dstA[e];
        if ((unsigned)s < (unsigned)NNODES && (unsigned)d < (unsigned)NNODES) {
            int pos = atomicAdd(&cursor[d], 1);
            eSrc[pos] = s;
        }
    }
}

__device__ inline void acc8(const uint4& v, float* acc) {
    const __half2* hp = (const __half2*)&v;
#pragma unroll
    for (int i = 0; i < 4; ++i) {
        float2 f = __half22float2(hp[i]);
        acc[2 * i]     += f.x;
        acc[2 * i + 1] += f.y;
    }
}

// 16 waves/block, wave per node. 8 lane-groups x 16B cover a 128B f16 row, so
// 8 edge rows are in flight per load instruction. Group xor-reduce; agg row
// staged through LDS; MLP reads agg via uniform-address float4 broadcasts.
// svs[node] = dinv[node] * dot(relu(agg@W1 + b1), W2)
__global__ __launch_bounds__(1024) void k_agg_mlp(const uint4* __restrict__ Xs4,
                                                  const int* __restrict__ rowPtr,
                                                  const int* __restrict__ eSrc,
                                                  const float* __restrict__ dinv,
                                                  const float* __restrict__ W1,
                                                  const float* __restrict__ b1,
                                                  const float* __restrict__ W2,
                                                  float* __restrict__ svs, int n) {
    __shared__ float W1s[INF * HID];   // 32 KB, k-major (lane-stride-1 reads)
    __shared__ float b1s[HID];
    __shared__ float W2s[HID];
    __shared__ int recs[REC_CAP];      // 8 KB
    __shared__ float aggL[NPB][INF];   // 4 KB
    for (int i = threadIdx.x; i < INF * HID / 4; i += blockDim.x)
        ((float4*)W1s)[i] = ((const float4*)W1)[i];
    if (threadIdx.x < HID) {
        b1s[threadIdx.x] = b1[threadIdx.x];
        W2s[threadIdx.x] = W2[threadIdx.x];
    }

    int n0 = blockIdx.x * NPB;
    int rBeg = rowPtr[n0];
    int rEnd = rowPtr[min(n0 + NPB, n)];
    int total = min(rEnd - rBeg, REC_CAP);
    for (int i = threadIdx.x; i < total; i += blockDim.x)
        recs[i] = eSrc[rBeg + i];  // coalesced 4B/lane
    __syncthreads();

    int lane = threadIdx.x & 63;
    int wid = threadIdx.x >> 6;
    int r = lane & 7;   // 16B chunk within row (features 8r..8r+8)
    int g = lane >> 3;  // edge-slot group
    int node = n0 + wid;
    float dD = 0.0f;

    if (node < n) {
        dD = dinv[node];
        int beg = rowPtr[node];
        int end = rowPtr[node + 1];
        float acc[8] = {0, 0, 0, 0, 0, 0, 0, 0};
        if (g == 0) {  // self-loop term: + Xs[node]
            uint4 v = Xs4[(size_t)node * 8 + r];
            acc8(v, acc);
        }
        int lend = end - rBeg;
        for (int jj = (beg - rBeg) + g; jj < lend; jj += 8) {
            int src = (jj < REC_CAP) ? recs[jj] : eSrc[rBeg + jj];
            uint4 v = Xs4[(size_t)src * 8 + r];
            acc8(v, acc);
        }
#pragma unroll
        for (int off = 8; off <= 32; off <<= 1) {
#pragma unroll
            for (int c = 0; c < 8; ++c) acc[c] += __shfl_xor(acc[c], off, 64);
        }
        if (lane < 8) {  // lane == r holds feature chunk r
            float4 lo, hi;
            lo.x = dD * acc[0]; lo.y = dD * acc[1]; lo.z = dD * acc[2]; lo.w = dD * acc[3];
            hi.x = dD * acc[4]; hi.y = dD * acc[5]; hi.z = dD * acc[6]; hi.w = dD * acc[7];
            *(float4*)&aggL[wid][lane * 8]     = lo;
            *(float4*)&aggL[wid][lane * 8 + 4] = hi;
        }
    }
    __syncthreads();

    if (node < n) {
        float a0 = b1s[lane], a1 = b1s[64 + lane];
#pragma unroll
        for (int rr = 0; rr < 8; ++rr) {
            float4 xlo = *(const float4*)&aggL[wid][rr * 8];      // uniform: broadcast
            float4 xhi = *(const float4*)&aggL[wid][rr * 8 + 4];
            int k0 = rr * 8;
            a0 = fmaf(xlo.x, W1s[(k0 + 0) * HID + lane], a0);
            a1 = fmaf(xlo.x, W1s[(k0 + 0) * HID + 64 + lane], a1);
            a0 = fmaf(xlo.y, W1s[(k0 + 1) * HID + lane], a0);
            a1 = fmaf(xlo.y, W1s[(k0 + 1) * HID + 64 + lane], a1);
            a0 = fmaf(xlo.z, W1s[(k0 + 2) * HID + lane], a0);
            a1 = fmaf(xlo.z, W1s[(k0 + 2) * HID + 64 + lane], a1);
            a0 = fmaf(xlo.w, W1s[(k0 + 3) * HID + lane], a0);
            a1 = fmaf(xlo.w, W1s[(k0 + 3) * HID + 64 + lane], a1);
            a0 = fmaf(xhi.x, W1s[(k0 + 4) * HID + lane], a0);
            a1 = fmaf(xhi.x, W1s[(k0 + 4) * HID + 64 + lane], a1);
            a0 = fmaf(xhi.y, W1s[(k0 + 5) * HID + lane], a0);
            a1 = fmaf(xhi.y, W1s[(k0 + 5) * HID + 64 + lane], a1);
            a0 = fmaf(xhi.z, W1s[(k0 + 6) * HID + lane], a0);
            a1 = fmaf(xhi.z, W1s[(k0 + 6) * HID + 64 + lane], a1);
            a0 = fmaf(xhi.w, W1s[(k0 + 7) * HID + lane], a0);
            a1 = fmaf(xhi.w, W1s[(k0 + 7) * HID + 64 + lane], a1);
        }
        float h0 = fmaxf(a0, 0.0f);
        float h1 = fmaxf(a1, 0.0f);
        float p = h0 * W2s[lane] + h1 * W2s[64 + lane];
#pragma unroll
        for (int off = 32; off > 0; off >>= 1) p += __shfl_xor(p, off, 64);
        if (lane == 0) svs[node] = dD * p;   // pre-scaled for layer 2
    }
}

// 4 nodes per wave: out[d] = dD*(sum svs[src] + svs[d]) + b2
__global__ __launch_bounds__(256) void k_out(const int* __restrict__ rowPtr,
                                             const int* __restrict__ eSrc,
                                             const float* __restrict__ dinv,
                                             const float* __restrict__ svs,
                                             const float* __restrict__ b2,
                                             float* __restrict__ out, int n) {
    int t = blockIdx.x * blockDim.x + threadIdx.x;
    int node = t >> 4;
    int r = t & 15;
    if (node >= n) return;
    int beg = rowPtr[node];
    int end = rowPtr[node + 1];
    float p = 0.0f;
    for (int j = beg + r; j < end; j += 16) p += svs[eSrc[j]];
    p += __shfl_xor(p, 1, 16);
    p += __shfl_xor(p, 2, 16);
    p += __shfl_xor(p, 4, 16);
    p += __shfl_xor(p, 8, 16);
    if (r == 0) {
        float dD = dinv[node];
        out[node] = fmaf(dD, p + svs[node], b2[0]);
    }
}

extern "C" void kernel_launch(void* const* d_in, const int* in_sizes, int n_in,
                              void* d_out, int out_size, void* d_ws, size_t ws_size,
                              hipStream_t stream) {
    const float* X  = (const float*)d_in[0];
    const int*   ei = (const int*)d_in[1];   // int32 (jax x64 disabled)
    const float* W1 = (const float*)d_in[2];
    const float* b1 = (const float*)d_in[3];
    const float* W2 = (const float*)d_in[4];
    const float* b2 = (const float*)d_in[5];

    int N = in_sizes[0] / INF;  // 100000
    int E = in_sizes[1] / 2;    // 1600000
    const int* srcA = ei;
    const int* dstA = ei + E;

    // workspace layout (Xs first, 16B aligned)
    uint4* Xs4    = (uint4*)d_ws;                 // N*8 uint4 = 12.8 MB
    int*   eSrc   = (int*)(Xs4 + (size_t)N * 8);  // E
    int*   counts = eSrc + E;                     // N
    int*   rowPtr = counts + N;                   // N+1
    int*   cursor = rowPtr + N + 1;               // N
    int*   bsums  = cursor + N;                   // 256
    float* dinv   = (float*)(bsums + 256);        // N
    float* svs    = dinv + N;                     // N
    float* out    = (float*)d_out;

    int nbN = (N + 255) / 256;
    int nbE = (E + 255) / 256;
    int nb1 = (N + 1023) / 1024;

    hipMemsetAsync(counts, 0, (size_t)N * sizeof(int), stream);
    k_hist<<<nbE, 256, 0, stream>>>(dstA, counts, E);
    k_scan1<<<nb1, 256, 0, stream>>>(counts, rowPtr, bsums, N);
    k_scan2<<<1, 256, 0, stream>>>(bsums, nb1);
    k_finalize<<<nbN, 256, 0, stream>>>(rowPtr, cursor, bsums, counts, dinv, N, E);
    k_prescale<<<(N * 8 + 255) / 256, 256, 0, stream>>>((const float4*)X, dinv, Xs4, N);
    k_fill<<<nbE, 256, 0, stream>>>(srcA, dstA, cursor, eSrc, E);
    k_agg_mlp<<<(N + NPB - 1) / NPB, 1024, 0, stream>>>(Xs4, rowPtr, eSrc, dinv,
                                                        W1, b1, W2, svs, N);
    k_out<<<(N * 16 + 255) / 256, 256, 0, stream>>>(rowPtr, eSrc, dinv, svs, b2, out, N);
}

// Round 8
// 204.375 us; speedup vs baseline: 3.0084x; 1.6637x over previous
//
#include <hip/hip_runtime.h>
#include <hip/hip_fp16.h>

// GCN 2-layer forward — CSR-gather with f16 pre-scaled features.
// CSR build is a 2-level LDS-staged counting sort (no random global scatter):
//   k_thist: per-tile x per-bucket histogram (LDS)     -> tileCnt[t][b]
//   k_bscan: bucket-major scan                         -> tileBase[t][b], bBase[b]
//   k_bin:   coalesced binning, 4B packed (dstLoc,src) -> binned[]
//   k_csr:   per-bucket LDS counting sort              -> rowPtr, dinv, eSrc
// Aggregation: agg[d] = dinv_d*(sum Xs[src] + Xs[d]) with Xs = dinv*X in f16;
// layer 2 via svs = dinv * dot(relu(agg@W1+b1), W2), scalar gather + b2.

#define NNODES 100000
#define INF 64
#define HID 128
#define NPB 16        // nodes per block in k_agg_mlp
#define REC_CAP 2048  // LDS record capacity (ints)
#define MAXBK 128     // max buckets (1024 nodes each)
#define TILE_E 16384  // edges per binning tile (1024 thr x 16)

// A1: per-tile per-bucket histogram
__global__ __launch_bounds__(1024) void k_thist(const int* __restrict__ dstA,
                                                int* __restrict__ tileCnt, int nE) {
    __shared__ int h[MAXBK];
    int tid = threadIdx.x;
    if (tid < MAXBK) h[tid] = 0;
    __syncthreads();
    int base = blockIdx.x * TILE_E;
#pragma unroll
    for (int k = 0; k < 16; ++k) {
        int e = base + k * 1024 + tid;
        if (e < nE) atomicAdd(&h[((unsigned)dstA[e]) >> 10], 1);
    }
    __syncthreads();
    if (tid < MAXBK) tileCnt[blockIdx.x * MAXBK + tid] = h[tid];
}

// A2: bucket-major scan of tileCnt -> tileBase, bucket bases, rowPtr[n]=total
__global__ __launch_bounds__(MAXBK) void k_bscan(const int* __restrict__ tileCnt,
                                                 int* __restrict__ tileBase,
                                                 int* __restrict__ bBase,
                                                 int* __restrict__ rowPtr,
                                                 int n, int nbk, int nt) {
    __shared__ int tmp[MAXBK];
    int b = threadIdx.x;
    int s = 0;
    for (int t = 0; t < nt; ++t) s += tileCnt[t * MAXBK + b];
    tmp[b] = s;
    __syncthreads();
    int own = s;
    for (int off = 1; off < MAXBK; off <<= 1) {
        int u = (b >= off) ? tmp[b - off] : 0;
        __syncthreads();
        tmp[b] += u;
        __syncthreads();
    }
    int colBase = tmp[b] - own;
    if (b < nbk) bBase[b] = colBase;
    if (b == nbk - 1) { bBase[nbk] = tmp[b]; rowPtr[n] = tmp[b]; }
    int run = colBase;
    for (int t = 0; t < nt; ++t) {
        tileBase[t * MAXBK + b] = run;
        run += tileCnt[t * MAXBK + b];
    }
}

// A3: binning scatter; writes dense per-(tile,bucket) runs (no amplification)
__global__ __launch_bounds__(1024) void k_bin(const int* __restrict__ srcA,
                                              const int* __restrict__ dstA,
                                              const int* __restrict__ tileBase,
                                              unsigned* __restrict__ binned, int nE) {
    __shared__ int myb[MAXBK];
    __shared__ int cur[MAXBK];
    int tid = threadIdx.x;
    if (tid < MAXBK) {
        myb[tid] = tileBase[blockIdx.x * MAXBK + tid];
        cur[tid] = 0;
    }
    __syncthreads();
    int base = blockIdx.x * TILE_E;
#pragma unroll
    for (int k = 0; k < 16; ++k) {
        int e = base + k * 1024 + tid;
        if (e < nE) {
            int d = dstA[e];
            int s = srcA[e];
            int bk = ((unsigned)d) >> 10;
            int off = atomicAdd(&cur[bk], 1);
            binned[myb[bk] + off] = ((unsigned)(d & 1023) << 17) | (unsigned)s;
        }
    }
}

// B: per-bucket counting sort -> rowPtr, dinv, eSrc (all writes L2-local)
__global__ __launch_bounds__(1024) void k_csr(const unsigned* __restrict__ binned,
                                              const int* __restrict__ bBase,
                                              int* __restrict__ rowPtr,
                                              float* __restrict__ dinv,
                                              int* __restrict__ eSrc, int n) {
    __shared__ int hist[1024];
    __shared__ int curs[1024];
    int tid = threadIdx.x;
    int b = blockIdx.x;
    int lo = bBase[b], hi = bBase[b + 1];
    hist[tid] = 0;
    __syncthreads();
    for (int i = lo + tid; i < hi; i += 1024)
        atomicAdd(&hist[binned[i] >> 17], 1);
    __syncthreads();
    int own = hist[tid];
    for (int off = 1; off < 1024; off <<= 1) {
        int u = (tid >= off) ? hist[tid - off] : 0;
        __syncthreads();
        hist[tid] += u;
        __syncthreads();
    }
    int pos0 = lo + hist[tid] - own;
    curs[tid] = pos0;
    int node = (b << 10) + tid;
    if (node < n) {
        rowPtr[node] = pos0;
        dinv[node] = rsqrtf((float)(own + 1));  // +1 self loop
    }
    __syncthreads();
    for (int i = lo + tid; i < hi; i += 1024) {
        unsigned v = binned[i];
        int pos = atomicAdd(&curs[v >> 17], 1);
        eSrc[pos] = (int)(v & 0x1FFFFu);
    }
}

// Xs[node][64] (f16) = dinv[node] * X[node][64]; row = 8 x uint4 (128 B)
__global__ void k_prescale(const float4* __restrict__ X4, const float* __restrict__ dinv,
                           uint4* __restrict__ Xs4, int n) {
    int t = blockIdx.x * blockDim.x + threadIdx.x;
    if (t >= n * 8) return;
    int node = t >> 3;
    int r = t & 7;
    float dD = dinv[node];
    float4 a = X4[(size_t)node * 16 + r * 2];
    float4 b = X4[(size_t)node * 16 + r * 2 + 1];
    __half2 h0 = __float22half2_rn(make_float2(dD * a.x, dD * a.y));
    __half2 h1 = __float22half2_rn(make_float2(dD * a.z, dD * a.w));
    __half2 h2 = __float22half2_rn(make_float2(dD * b.x, dD * b.y));
    __half2 h3 = __float22half2_rn(make_float2(dD * b.z, dD * b.w));
    uint4 o;
    o.x = *(unsigned*)&h0; o.y = *(unsigned*)&h1;
    o.z = *(unsigned*)&h2; o.w = *(unsigned*)&h3;
    Xs4[t] = o;
}

__device__ inline void acc8(const uint4& v, float* acc) {
    const __half2* hp = (const __half2*)&v;
#pragma unroll
    for (int i = 0; i < 4; ++i) {
        float2 f = __half22float2(hp[i]);
        acc[2 * i]     += f.x;
        acc[2 * i + 1] += f.y;
    }
}

// 16 waves/block, wave per node. 8 lane-groups x 16B cover a 128B f16 row, so
// 8 edge rows are in flight per load instruction. Group xor-reduce; agg row
// staged through LDS; MLP reads agg via uniform-address float4 broadcasts.
// svs[node] = dinv[node] * dot(relu(agg@W1 + b1), W2)
__global__ __launch_bounds__(1024) void k_agg_mlp(const uint4* __restrict__ Xs4,
                                                  const int* __restrict__ rowPtr,
                                                  const int* __restrict__ eSrc,
                                                  const float* __restrict__ dinv,
                                                  const float* __restrict__ W1,
                                                  const float* __restrict__ b1,
                                                  const float* __restrict__ W2,
                                                  float* __restrict__ svs, int n) {
    __shared__ float W1s[INF * HID];   // 32 KB, k-major (lane-stride-1 reads)
    __shared__ float b1s[HID];
    __shared__ float W2s[HID];
    __shared__ int recs[REC_CAP];      // 8 KB
    __shared__ float aggL[NPB][INF];   // 4 KB
    for (int i = threadIdx.x; i < INF * HID / 4; i += blockDim.x)
        ((float4*)W1s)[i] = ((const float4*)W1)[i];
    if (threadIdx.x < HID) {
        b1s[threadIdx.x] = b1[threadIdx.x];
        W2s[threadIdx.x] = W2[threadIdx.x];
    }

    int n0 = blockIdx.x * NPB;
    int rBeg = rowPtr[n0];
    int rEnd = rowPtr[min(n0 + NPB, n)];
    int total = min(rEnd - rBeg, REC_CAP);
    for (int i = threadIdx.x; i < total; i += blockDim.x)
        recs[i] = eSrc[rBeg + i];  // coalesced 4B/lane
    __syncthreads();

    int lane = threadIdx.x & 63;
    int wid = threadIdx.x >> 6;
    int r = lane & 7;   // 16B chunk within row (features 8r..8r+8)
    int g = lane >> 3;  // edge-slot group
    int node = n0 + wid;
    float dD = 0.0f;

    if (node < n) {
        dD = dinv[node];
        int beg = rowPtr[node];
        int end = rowPtr[node + 1];
        float acc[8] = {0, 0, 0, 0, 0, 0, 0, 0};
        if (g == 0) {  // self-loop term: + Xs[node]
            uint4 v = Xs4[(size_t)node * 8 + r];
            acc8(v, acc);
        }
        int lend = end - rBeg;
        for (int jj = (beg - rBeg) + g; jj < lend; jj += 8) {
            int src = (jj < REC_CAP) ? recs[jj] : eSrc[rBeg + jj];
            uint4 v = Xs4[(size_t)src * 8 + r];
            acc8(v, acc);
        }
#pragma unroll
        for (int off = 8; off <= 32; off <<= 1) {
#pragma unroll
            for (int c = 0; c < 8; ++c) acc[c] += __shfl_xor(acc[c], off, 64);
        }
        if (lane < 8) {  // lane == r holds feature chunk r
            float4 lo, hi;
            lo.x = dD * acc[0]; lo.y = dD * acc[1]; lo.z = dD * acc[2]; lo.w = dD * acc[3];
            hi.x = dD * acc[4]; hi.y = dD * acc[5]; hi.z = dD * acc[6]; hi.w = dD * acc[7];
            *(float4*)&aggL[wid][lane * 8]     = lo;
            *(float4*)&aggL[wid][lane * 8 + 4] = hi;
        }
    }
    __syncthreads();

    if (node < n) {
        float a0 = b1s[lane], a1 = b1s[64 + lane];
#pragma unroll
        for (int rr = 0; rr < 8; ++rr) {
            float4 xlo = *(const float4*)&aggL[wid][rr * 8];      // uniform: broadcast
            float4 xhi = *(const float4*)&aggL[wid][rr * 8 + 4];
            int k0 = rr * 8;
            a0 = fmaf(xlo.x, W1s[(k0 + 0) * HID + lane], a0);
            a1 = fmaf(xlo.x, W1s[(k0 + 0) * HID + 64 + lane], a1);
            a0 = fmaf(xlo.y, W1s[(k0 + 1) * HID + lane], a0);
            a1 = fmaf(xlo.y, W1s[(k0 + 1) * HID + 64 + lane], a1);
            a0 = fmaf(xlo.z, W1s[(k0 + 2) * HID + lane], a0);
            a1 = fmaf(xlo.z, W1s[(k0 + 2) * HID + 64 + lane], a1);
            a0 = fmaf(xlo.w, W1s[(k0 + 3) * HID + lane], a0);
            a1 = fmaf(xlo.w, W1s[(k0 + 3) * HID + 64 + lane], a1);
            a0 = fmaf(xhi.x, W1s[(k0 + 4) * HID + lane], a0);
            a1 = fmaf(xhi.x, W1s[(k0 + 4) * HID + 64 + lane], a1);
            a0 = fmaf(xhi.y, W1s[(k0 + 5) * HID + lane], a0);
            a1 = fmaf(xhi.y, W1s[(k0 + 5) * HID + 64 + lane], a1);
            a0 = fmaf(xhi.z, W1s[(k0 + 6) * HID + lane], a0);
            a1 = fmaf(xhi.z, W1s[(k0 + 6) * HID + 64 + lane], a1);
            a0 = fmaf(xhi.w, W1s[(k0 + 7) * HID + lane], a0);
            a1 = fmaf(xhi.w, W1s[(k0 + 7) * HID + 64 + lane], a1);
        }
        float h0 = fmaxf(a0, 0.0f);
        float h1 = fmaxf(a1, 0.0f);
        float p = h0 * W2s[lane] + h1 * W2s[64 + lane];
#pragma unroll
        for (int off = 32; off > 0; off >>= 1) p += __shfl_xor(p, off, 64);
        if (lane == 0) svs[node] = dD * p;   // pre-scaled for layer 2
    }
}

// 4 nodes per wave: out[d] = dD*(sum svs[src] + svs[d]) + b2
__global__ __launch_bounds__(256) void k_out(const int* __restrict__ rowPtr,
                                             const int* __restrict__ eSrc,
                                             const float* __restrict__ dinv,
                                             const float* __restrict__ svs,
                                             const float* __restrict__ b2,
                                             float* __restrict__ out, int n) {
    int t = blockIdx.x * blockDim.x + threadIdx.x;
    int node = t >> 4;
    int r = t & 15;
    if (node >= n) return;
    int beg = rowPtr[node];
    int end = rowPtr[node + 1];
    float p = 0.0f;
    for (int j = beg + r; j < end; j += 16) p += svs[eSrc[j]];
    p += __shfl_xor(p, 1, 16);
    p += __shfl_xor(p, 2, 16);
    p += __shfl_xor(p, 4, 16);
    p += __shfl_xor(p, 8, 16);
    if (r == 0) {
        float dD = dinv[node];
        out[node] = fmaf(dD, p + svs[node], b2[0]);
    }
}

extern "C" void kernel_launch(void* const* d_in, const int* in_sizes, int n_in,
                              void* d_out, int out_size, void* d_ws, size_t ws_size,
                              hipStream_t stream) {
    const float* X  = (const float*)d_in[0];
    const int*   ei = (const int*)d_in[1];   // int32 (jax x64 disabled)
    const float* W1 = (const float*)d_in[2];
    const float* b1 = (const float*)d_in[3];
    const float* W2 = (const float*)d_in[4];
    const float* b2 = (const float*)d_in[5];

    int N = in_sizes[0] / INF;  // 100000
    int E = in_sizes[1] / 2;    // 1600000
    const int* srcA = ei;
    const int* dstA = ei + E;

    int nt  = (E + TILE_E - 1) / TILE_E;  // 98 tiles
    int nbk = (N + 1023) >> 10;           // 98 buckets

    // workspace layout (Xs first, 16B aligned)
    uint4*    Xs4      = (uint4*)d_ws;                    // N*8 uint4 = 12.8 MB
    unsigned* binned   = (unsigned*)(Xs4 + (size_t)N * 8);// E
    int*      eSrc     = (int*)(binned + E);              // E
    int*      tileCnt  = eSrc + E;                        // nt*MAXBK
    int*      tileBase = tileCnt + nt * MAXBK;            // nt*MAXBK
    int*      bBase    = tileBase + nt * MAXBK;           // nbk+1
    int*      rowPtr   = bBase + nbk + 1;                 // N+1
    float*    dinv     = (float*)(rowPtr + N + 1);        // N
    float*    svs      = dinv + N;                        // N
    float*    out      = (float*)d_out;

    k_thist<<<nt, 1024, 0, stream>>>(dstA, tileCnt, E);
    k_bscan<<<1, MAXBK, 0, stream>>>(tileCnt, tileBase, bBase, rowPtr, N, nbk, nt);
    k_bin<<<nt, 1024, 0, stream>>>(srcA, dstA, tileBase, binned, E);
    k_csr<<<nbk, 1024, 0, stream>>>(binned, bBase, rowPtr, dinv, eSrc, N);
    k_prescale<<<(N * 8 + 255) / 256, 256, 0, stream>>>((const float4*)X, dinv, Xs4, N);
    k_agg_mlp<<<(N + NPB - 1) / NPB, 1024, 0, stream>>>(Xs4, rowPtr, eSrc, dinv,
                                                        W1, b1, W2, svs, N);
    k_out<<<(N * 16 + 255) / 256, 256, 0, stream>>>(rowPtr, eSrc, dinv, svs, b2, out, N);
}

// Round 9
// 139.065 us; speedup vs baseline: 4.4212x; 1.4696x over previous
//
#include <hip/hip_runtime.h>
#include <hip/hip_fp16.h>

// GCN 2-layer forward — f16 CSR-gather (pure) + MFMA MLP.
// CSR build: 2-level LDS-staged counting sort (k_thist/k_bscan/k_bin/k_csr).
// k_agg: 8 lanes/node, 8 nodes/wave, no barriers -> aggH[N][64] f16.
// k_mlp: mfma_f32_16x16x32_f16, 16 nodes/wave -> svs = dinv*relu(agg@W1+b1)@W2.
// k_out: scalar CSR gather of svs.

#define NNODES 100000
#define INF 64
#define HID 128
#define MAXBK 128     // max buckets (1024 nodes each)
#define TILE_E 16384  // edges per binning tile (1024 thr x 16)

using half8 = __attribute__((ext_vector_type(8))) _Float16;
using f32x4 = __attribute__((ext_vector_type(4))) float;

// A1: per-tile per-bucket histogram
__global__ __launch_bounds__(1024) void k_thist(const int* __restrict__ dstA,
                                                int* __restrict__ tileCnt, int nE) {
    __shared__ int h[MAXBK];
    int tid = threadIdx.x;
    if (tid < MAXBK) h[tid] = 0;
    __syncthreads();
    int base = blockIdx.x * TILE_E;
#pragma unroll
    for (int k = 0; k < 16; ++k) {
        int e = base + k * 1024 + tid;
        if (e < nE) atomicAdd(&h[((unsigned)dstA[e]) >> 10], 1);
    }
    __syncthreads();
    if (tid < MAXBK) tileCnt[blockIdx.x * MAXBK + tid] = h[tid];
}

// A2: bucket-major scan of tileCnt -> tileBase, bucket bases, rowPtr[n]=total
__global__ __launch_bounds__(MAXBK) void k_bscan(const int* __restrict__ tileCnt,
                                                 int* __restrict__ tileBase,
                                                 int* __restrict__ bBase,
                                                 int* __restrict__ rowPtr,
                                                 int n, int nbk, int nt) {
    __shared__ int tmp[MAXBK];
    int b = threadIdx.x;
    int s = 0;
    for (int t = 0; t < nt; ++t) s += tileCnt[t * MAXBK + b];
    tmp[b] = s;
    __syncthreads();
    int own = s;
    for (int off = 1; off < MAXBK; off <<= 1) {
        int u = (b >= off) ? tmp[b - off] : 0;
        __syncthreads();
        tmp[b] += u;
        __syncthreads();
    }
    int colBase = tmp[b] - own;
    if (b < nbk) bBase[b] = colBase;
    if (b == nbk - 1) { bBase[nbk] = tmp[b]; rowPtr[n] = tmp[b]; }
    int run = colBase;
    for (int t = 0; t < nt; ++t) {
        tileBase[t * MAXBK + b] = run;
        run += tileCnt[t * MAXBK + b];
    }
}

// A3: binning scatter; writes dense per-(tile,bucket) runs (no amplification)
__global__ __launch_bounds__(1024) void k_bin(const int* __restrict__ srcA,
                                              const int* __restrict__ dstA,
                                              const int* __restrict__ tileBase,
                                              unsigned* __restrict__ binned, int nE) {
    __shared__ int myb[MAXBK];
    __shared__ int cur[MAXBK];
    int tid = threadIdx.x;
    if (tid < MAXBK) {
        myb[tid] = tileBase[blockIdx.x * MAXBK + tid];
        cur[tid] = 0;
    }
    __syncthreads();
    int base = blockIdx.x * TILE_E;
#pragma unroll
    for (int k = 0; k < 16; ++k) {
        int e = base + k * 1024 + tid;
        if (e < nE) {
            int d = dstA[e];
            int s = srcA[e];
            int bk = ((unsigned)d) >> 10;
            int off = atomicAdd(&cur[bk], 1);
            binned[myb[bk] + off] = ((unsigned)(d & 1023) << 17) | (unsigned)s;
        }
    }
}

// B: per-bucket counting sort -> rowPtr, dinv, eSrc (all writes L2-local)
__global__ __launch_bounds__(1024) void k_csr(const unsigned* __restrict__ binned,
                                              const int* __restrict__ bBase,
                                              int* __restrict__ rowPtr,
                                              float* __restrict__ dinv,
                                              int* __restrict__ eSrc, int n) {
    __shared__ int hist[1024];
    __shared__ int curs[1024];
    int tid = threadIdx.x;
    int b = blockIdx.x;
    int lo = bBase[b], hi = bBase[b + 1];
    hist[tid] = 0;
    __syncthreads();
    for (int i = lo + tid; i < hi; i += 1024)
        atomicAdd(&hist[binned[i] >> 17], 1);
    __syncthreads();
    int own = hist[tid];
    for (int off = 1; off < 1024; off <<= 1) {
        int u = (tid >= off) ? hist[tid - off] : 0;
        __syncthreads();
        hist[tid] += u;
        __syncthreads();
    }
    int pos0 = lo + hist[tid] - own;
    curs[tid] = pos0;
    int node = (b << 10) + tid;
    if (node < n) {
        rowPtr[node] = pos0;
        dinv[node] = rsqrtf((float)(own + 1));  // +1 self loop
    }
    __syncthreads();
    for (int i = lo + tid; i < hi; i += 1024) {
        unsigned v = binned[i];
        int pos = atomicAdd(&curs[v >> 17], 1);
        eSrc[pos] = (int)(v & 0x1FFFFu);
    }
}

// Xs[node][64] (f16) = dinv[node] * X[node][64]; row = 8 x uint4 (128 B)
__global__ void k_prescale(const float4* __restrict__ X4, const float* __restrict__ dinv,
                           uint4* __restrict__ Xs4, int n) {
    int t = blockIdx.x * blockDim.x + threadIdx.x;
    if (t >= n * 8) return;
    int node = t >> 3;
    int r = t & 7;
    float dD = dinv[node];
    float4 a = X4[(size_t)node * 16 + r * 2];
    float4 b = X4[(size_t)node * 16 + r * 2 + 1];
    __half2 h0 = __float22half2_rn(make_float2(dD * a.x, dD * a.y));
    __half2 h1 = __float22half2_rn(make_float2(dD * a.z, dD * a.w));
    __half2 h2 = __float22half2_rn(make_float2(dD * b.x, dD * b.y));
    __half2 h3 = __float22half2_rn(make_float2(dD * b.z, dD * b.w));
    uint4 o;
    o.x = *(unsigned*)&h0; o.y = *(unsigned*)&h1;
    o.z = *(unsigned*)&h2; o.w = *(unsigned*)&h3;
    Xs4[t] = o;
}

// W1t[n][k] f16 = W1[k][n]  (transposed, so MFMA B-frags are contiguous 16B)
__global__ void k_wprep(const float* __restrict__ W1, _Float16* __restrict__ W1t) {
    int i = blockIdx.x * blockDim.x + threadIdx.x;
    if (i >= HID * INF) return;
    int nCol = i >> 6;   // 0..127
    int k = i & 63;
    W1t[i] = (_Float16)W1[k * HID + nCol];
}

__device__ inline void acc8_add(const uint4& v, float* acc) {
    const __half2* hp = (const __half2*)&v;
#pragma unroll
    for (int i = 0; i < 4; ++i) {
        float2 f = __half22float2(hp[i]);
        acc[2 * i]     += f.x;
        acc[2 * i + 1] += f.y;
    }
}

// Pure gather: 8 lanes per node (lane r covers features 8r..8r+8), node = tid>>3.
// agg[d] = dD*(Xs[d] + sum_e Xs[src]); written as f16 row (coalesced 1KB/wave).
__global__ __launch_bounds__(256) void k_agg(const uint4* __restrict__ Xs4,
                                             const int* __restrict__ rowPtr,
                                             const int* __restrict__ eSrc,
                                             const float* __restrict__ dinv,
                                             uint4* __restrict__ aggH, int n) {
    int t = blockIdx.x * blockDim.x + threadIdx.x;
    int node = t >> 3;
    int r = t & 7;
    if (node >= n) return;
    int beg = rowPtr[node];
    int end = rowPtr[node + 1];
    float dD = dinv[node];

    float acc[8];
    {   // self-loop init
        uint4 v = Xs4[(size_t)node * 8 + r];
        const __half2* hp = (const __half2*)&v;
#pragma unroll
        for (int i = 0; i < 4; ++i) {
            float2 f = __half22float2(hp[i]);
            acc[2 * i] = f.x;
            acc[2 * i + 1] = f.y;
        }
    }
    int j = beg;
    for (; j + 3 < end; j += 4) {
        int s0 = eSrc[j], s1 = eSrc[j + 1], s2 = eSrc[j + 2], s3 = eSrc[j + 3];
        uint4 v0 = Xs4[(size_t)s0 * 8 + r];
        uint4 v1 = Xs4[(size_t)s1 * 8 + r];
        uint4 v2 = Xs4[(size_t)s2 * 8 + r];
        uint4 v3 = Xs4[(size_t)s3 * 8 + r];
        acc8_add(v0, acc); acc8_add(v1, acc); acc8_add(v2, acc); acc8_add(v3, acc);
    }
    for (; j < end; ++j) {
        int s = eSrc[j];
        uint4 v = Xs4[(size_t)s * 8 + r];
        acc8_add(v, acc);
    }
    __half2 h0 = __float22half2_rn(make_float2(dD * acc[0], dD * acc[1]));
    __half2 h1 = __float22half2_rn(make_float2(dD * acc[2], dD * acc[3]));
    __half2 h2 = __float22half2_rn(make_float2(dD * acc[4], dD * acc[5]));
    __half2 h3 = __float22half2_rn(make_float2(dD * acc[6], dD * acc[7]));
    uint4 o;
    o.x = *(unsigned*)&h0; o.y = *(unsigned*)&h1;
    o.z = *(unsigned*)&h2; o.w = *(unsigned*)&h3;
    aggH[(size_t)node * 8 + r] = o;
}

// MFMA MLP: wave per 16-node tile. 8 N-tiles x 2 K-steps of 16x16x32_f16.
// svs[m] = dinv[m] * sum_c relu(agg[m]@W1 + b1)[c] * W2[c]
__global__ __launch_bounds__(256) void k_mlp(const uint4* __restrict__ aggH,
                                             const uint4* __restrict__ W1t4,
                                             const float* __restrict__ b1,
                                             const float* __restrict__ W2,
                                             const float* __restrict__ dinv,
                                             float* __restrict__ svs, int nTiles) {
    int lane = threadIdx.x & 63;
    int tile = (blockIdx.x * blockDim.x + threadIdx.x) >> 6;
    if (tile >= nTiles) return;
    int m0 = tile * 16;
    int row = lane & 15;   // A row / B col / C col
    int kg = lane >> 4;    // k-group (8 halfs each)

    // B fragments (W1t row = output col, contiguous k) + per-col bias/W2
    half8 bf[8][2];
    float b1v[8], w2v[8];
#pragma unroll
    for (int nt = 0; nt < 8; ++nt) {
        int c = nt * 16 + row;
#pragma unroll
        for (int ks = 0; ks < 2; ++ks) {
            uint4 u = W1t4[c * 8 + ks * 4 + kg];
            bf[nt][ks] = __builtin_bit_cast(half8, u);
        }
        b1v[nt] = b1[c];
        w2v[nt] = W2[c];
    }

    // A fragments: row m0+row, k = ks*32 + kg*8 (+0..7)
    uint4 ua0 = aggH[(size_t)(m0 + row) * 8 + kg];
    uint4 ua1 = aggH[(size_t)(m0 + row) * 8 + 4 + kg];
    half8 a0 = __builtin_bit_cast(half8, ua0);
    half8 a1 = __builtin_bit_cast(half8, ua1);

    float p0 = 0.0f, p1 = 0.0f, p2 = 0.0f, p3 = 0.0f;
#pragma unroll
    for (int nt = 0; nt < 8; ++nt) {
        f32x4 acc = {0.0f, 0.0f, 0.0f, 0.0f};
        acc = __builtin_amdgcn_mfma_f32_16x16x32_f16(a0, bf[nt][0], acc, 0, 0, 0);
        acc = __builtin_amdgcn_mfma_f32_16x16x32_f16(a1, bf[nt][1], acc, 0, 0, 0);
        // C layout: col = lane&15 (= c above), row = kg*4 + j
        float h;
        h = fmaxf(acc[0] + b1v[nt], 0.0f); p0 = fmaf(h, w2v[nt], p0);
        h = fmaxf(acc[1] + b1v[nt], 0.0f); p1 = fmaf(h, w2v[nt], p1);
        h = fmaxf(acc[2] + b1v[nt], 0.0f); p2 = fmaf(h, w2v[nt], p2);
        h = fmaxf(acc[3] + b1v[nt], 0.0f); p3 = fmaf(h, w2v[nt], p3);
    }
    // reduce over the 16 col-lanes within each quarter
#pragma unroll
    for (int off = 1; off < 16; off <<= 1) {
        p0 += __shfl_xor(p0, off, 64);
        p1 += __shfl_xor(p1, off, 64);
        p2 += __shfl_xor(p2, off, 64);
        p3 += __shfl_xor(p3, off, 64);
    }
    if (row == 0) {
        int nd = m0 + kg * 4;
        svs[nd + 0] = dinv[nd + 0] * p0;
        svs[nd + 1] = dinv[nd + 1] * p1;
        svs[nd + 2] = dinv[nd + 2] * p2;
        svs[nd + 3] = dinv[nd + 3] * p3;
    }
}

// 4 nodes per wave: out[d] = dD*(sum svs[src] + svs[d]) + b2
__global__ __launch_bounds__(256) void k_out(const int* __restrict__ rowPtr,
                                             const int* __restrict__ eSrc,
                                             const float* __restrict__ dinv,
                                             const float* __restrict__ svs,
                                             const float* __restrict__ b2,
                                             float* __restrict__ out, int n) {
    int t = blockIdx.x * blockDim.x + threadIdx.x;
    int node = t >> 4;
    int r = t & 15;
    if (node >= n) return;
    int beg = rowPtr[node];
    int end = rowPtr[node + 1];
    float p = 0.0f;
    for (int j = beg + r; j < end; j += 16) p += svs[eSrc[j]];
    p += __shfl_xor(p, 1, 16);
    p += __shfl_xor(p, 2, 16);
    p += __shfl_xor(p, 4, 16);
    p += __shfl_xor(p, 8, 16);
    if (r == 0) {
        float dD = dinv[node];
        out[node] = fmaf(dD, p + svs[node], b2[0]);
    }
}

extern "C" void kernel_launch(void* const* d_in, const int* in_sizes, int n_in,
                              void* d_out, int out_size, void* d_ws, size_t ws_size,
                              hipStream_t stream) {
    const float* X  = (const float*)d_in[0];
    const int*   ei = (const int*)d_in[1];   // int32 (jax x64 disabled)
    const float* W1 = (const float*)d_in[2];
    const float* b1 = (const float*)d_in[3];
    const float* W2 = (const float*)d_in[4];
    const float* b2 = (const float*)d_in[5];

    int N = in_sizes[0] / INF;  // 100000
    int E = in_sizes[1] / 2;    // 1600000
    const int* srcA = ei;
    const int* dstA = ei + E;

    int nt  = (E + TILE_E - 1) / TILE_E;  // 98 tiles
    int nbk = (N + 1023) >> 10;           // 98 buckets

    // workspace layout (16B-aligned head first)
    uint4*    Xs4      = (uint4*)d_ws;                     // N*8 = 12.8 MB
    uint4*    aggH     = Xs4 + (size_t)N * 8;              // N*8 = 12.8 MB
    unsigned* binned   = (unsigned*)(aggH + (size_t)N * 8);// E
    int*      eSrc     = (int*)(binned + E);               // E
    _Float16* W1t      = (_Float16*)(eSrc + E);            // HID*INF = 16 KB
    int*      tileCnt  = (int*)(W1t + HID * INF);          // nt*MAXBK
    int*      tileBase = tileCnt + nt * MAXBK;             // nt*MAXBK
    int*      bBase    = tileBase + nt * MAXBK;            // nbk+1
    int*      rowPtr   = bBase + nbk + 1;                  // N+1
    float*    dinv     = (float*)(rowPtr + N + 1);         // N
    float*    svs      = dinv + N;                         // N
    float*    out      = (float*)d_out;

    int nTiles = (N + 15) / 16;  // 6250 (N divisible by 16)

    k_thist<<<nt, 1024, 0, stream>>>(dstA, tileCnt, E);
    k_bscan<<<1, MAXBK, 0, stream>>>(tileCnt, tileBase, bBase, rowPtr, N, nbk, nt);
    k_bin<<<nt, 1024, 0, stream>>>(srcA, dstA, tileBase, binned, E);
    k_csr<<<nbk, 1024, 0, stream>>>(binned, bBase, rowPtr, dinv, eSrc, N);
    k_wprep<<<(HID * INF + 255) / 256, 256, 0, stream>>>(W1, W1t);
    k_prescale<<<(N * 8 + 255) / 256, 256, 0, stream>>>((const float4*)X, dinv, Xs4, N);
    k_agg<<<(N * 8 + 255) / 256, 256, 0, stream>>>(Xs4, rowPtr, eSrc, dinv, aggH, N);
    k_mlp<<<(nTiles * 64 + 255) / 256, 256, 0, stream>>>(aggH, (const uint4*)W1t,
                                                         b1, W2, dinv, svs, nTiles);
    k_out<<<(N * 16 + 255) / 256, 256, 0, stream>>>(rowPtr, eSrc, dinv, svs, b2, out, N);
}

// Round 10
// 112.596 us; speedup vs baseline: 5.4605x; 1.2351x over previous
//
#include <hip/hip_runtime.h>
#include <hip/hip_fp16.h>

// GCN 2-layer forward — f16 CSR-gather fused with MFMA MLP.
// CSR build: 2-level LDS-staged counting sort (k_thist/k_bscan/k_bin/k_csr).
// k_agg_mlp: 32 nodes/block; phase1 gather -> swizzled LDS f16 rows;
//            phase2 waves 0-1 run two 16x16x32_f16 MFMA tiles from LDS.
// k_out: scalar CSR gather of svs.

#define NNODES 100000
#define INF 64
#define HID 128
#define MAXBK 128     // max buckets (1024 nodes each)
#define TILE_E 16384  // edges per binning tile (1024 thr x 16)

using half8 = __attribute__((ext_vector_type(8))) _Float16;
using f32x4 = __attribute__((ext_vector_type(4))) float;

// A1: per-tile per-bucket histogram
__global__ __launch_bounds__(1024) void k_thist(const int* __restrict__ dstA,
                                                int* __restrict__ tileCnt, int nE) {
    __shared__ int h[MAXBK];
    int tid = threadIdx.x;
    if (tid < MAXBK) h[tid] = 0;
    __syncthreads();
    int base = blockIdx.x * TILE_E;
#pragma unroll
    for (int k = 0; k < 16; ++k) {
        int e = base + k * 1024 + tid;
        if (e < nE) atomicAdd(&h[((unsigned)dstA[e]) >> 10], 1);
    }
    __syncthreads();
    if (tid < MAXBK) tileCnt[blockIdx.x * MAXBK + tid] = h[tid];
}

// A2: bucket-major scan (parallel: 8 tile-chunks x 128 buckets)
__global__ __launch_bounds__(1024) void k_bscan(const int* __restrict__ tileCnt,
                                                int* __restrict__ tileBase,
                                                int* __restrict__ bBase,
                                                int* __restrict__ rowPtr,
                                                int n, int nbk, int nt) {
    __shared__ int part[8][MAXBK];
    __shared__ int colScan[MAXBK];
    int b = threadIdx.x & (MAXBK - 1);
    int tg = threadIdx.x >> 7;               // 0..7
    int cpg = (nt + 7) / 8;
    int tlo = tg * cpg, thi = min(tlo + cpg, nt);
    int sum = 0;
    for (int t = tlo; t < thi; ++t) sum += tileCnt[t * MAXBK + b];
    part[tg][b] = sum;
    __syncthreads();
    int coff = 0;
    for (int g = 0; g < tg; ++g) coff += part[g][b];
    int ctot = 0;
#pragma unroll
    for (int g = 0; g < 8; ++g) ctot += part[g][b];
    if (tg == 0) colScan[b] = ctot;
    __syncthreads();
    // inclusive scan over b (all threads hit barriers)
    for (int off = 1; off < MAXBK; off <<= 1) {
        int u = (tg == 0 && b >= off) ? colScan[b - off] : 0;
        __syncthreads();
        if (tg == 0) colScan[b] += u;
        __syncthreads();
    }
    int colBase = colScan[b] - ctot;
    if (tg == 0 && b < nbk) bBase[b] = colBase;
    if (tg == 0 && b == nbk - 1) { bBase[nbk] = colScan[b]; rowPtr[n] = colScan[b]; }
    int run = colBase + coff;
    for (int t = tlo; t < thi; ++t) {
        tileBase[t * MAXBK + b] = run;
        run += tileCnt[t * MAXBK + b];
    }
}

// A3: binning scatter; writes dense per-(tile,bucket) runs (no amplification)
__global__ __launch_bounds__(1024) void k_bin(const int* __restrict__ srcA,
                                              const int* __restrict__ dstA,
                                              const int* __restrict__ tileBase,
                                              unsigned* __restrict__ binned, int nE) {
    __shared__ int myb[MAXBK];
    __shared__ int cur[MAXBK];
    int tid = threadIdx.x;
    if (tid < MAXBK) {
        myb[tid] = tileBase[blockIdx.x * MAXBK + tid];
        cur[tid] = 0;
    }
    __syncthreads();
    int base = blockIdx.x * TILE_E;
#pragma unroll
    for (int k = 0; k < 16; ++k) {
        int e = base + k * 1024 + tid;
        if (e < nE) {
            int d = dstA[e];
            int s = srcA[e];
            int bk = ((unsigned)d) >> 10;
            int off = atomicAdd(&cur[bk], 1);
            binned[myb[bk] + off] = ((unsigned)(d & 1023) << 17) | (unsigned)s;
        }
    }
}

// B: per-bucket counting sort -> rowPtr, dinv, eSrc (all writes L2-local)
__global__ __launch_bounds__(1024) void k_csr(const unsigned* __restrict__ binned,
                                              const int* __restrict__ bBase,
                                              int* __restrict__ rowPtr,
                                              float* __restrict__ dinv,
                                              int* __restrict__ eSrc, int n) {
    __shared__ int hist[1024];
    __shared__ int curs[1024];
    int tid = threadIdx.x;
    int b = blockIdx.x;
    int lo = bBase[b], hi = bBase[b + 1];
    hist[tid] = 0;
    __syncthreads();
    for (int i = lo + tid; i < hi; i += 1024)
        atomicAdd(&hist[binned[i] >> 17], 1);
    __syncthreads();
    int own = hist[tid];
    for (int off = 1; off < 1024; off <<= 1) {
        int u = (tid >= off) ? hist[tid - off] : 0;
        __syncthreads();
        hist[tid] += u;
        __syncthreads();
    }
    int pos0 = lo + hist[tid] - own;
    curs[tid] = pos0;
    int node = (b << 10) + tid;
    if (node < n) {
        rowPtr[node] = pos0;
        dinv[node] = rsqrtf((float)(own + 1));  // +1 self loop
    }
    __syncthreads();
    for (int i = lo + tid; i < hi; i += 1024) {
        unsigned v = binned[i];
        int pos = atomicAdd(&curs[v >> 17], 1);
        eSrc[pos] = (int)(v & 0x1FFFFu);
    }
}

// Xs[node][64] (f16) = dinv*X row; tail blocks build W1t[n][k] f16 = W1[k][n]
__global__ void k_prescale(const float4* __restrict__ X4, const float* __restrict__ dinv,
                           uint4* __restrict__ Xs4, const float* __restrict__ W1,
                           _Float16* __restrict__ W1t, int n) {
    int t = blockIdx.x * blockDim.x + threadIdx.x;
    if (t < n * 8) {
        int node = t >> 3;
        int r = t & 7;
        float dD = dinv[node];
        float4 a = X4[(size_t)node * 16 + r * 2];
        float4 b = X4[(size_t)node * 16 + r * 2 + 1];
        __half2 h0 = __float22half2_rn(make_float2(dD * a.x, dD * a.y));
        __half2 h1 = __float22half2_rn(make_float2(dD * a.z, dD * a.w));
        __half2 h2 = __float22half2_rn(make_float2(dD * b.x, dD * b.y));
        __half2 h3 = __float22half2_rn(make_float2(dD * b.z, dD * b.w));
        uint4 o;
        o.x = *(unsigned*)&h0; o.y = *(unsigned*)&h1;
        o.z = *(unsigned*)&h2; o.w = *(unsigned*)&h3;
        Xs4[t] = o;
    } else {
        int i = t - n * 8;
        if (i < HID * INF) {
            int nCol = i >> 6;   // 0..127
            int k = i & 63;
            W1t[i] = (_Float16)W1[k * HID + nCol];
        }
    }
}

__device__ inline void acc8_add(const uint4& v, float* acc) {
    const __half2* hp = (const __half2*)&v;
#pragma unroll
    for (int i = 0; i < 4; ++i) {
        float2 f = __half22float2(hp[i]);
        acc[2 * i]     += f.x;
        acc[2 * i + 1] += f.y;
    }
}

// Fused gather + MFMA MLP. 256 thr = 32 nodes/block.
// Phase 1: 8 lanes/node gather agg row (f32 acc) -> f16 row in swizzled LDS.
// Phase 2: waves 0-1 each run one 16-node MFMA tile (8 N-tiles x 2 K-steps),
//          A/B frags from LDS; epilogue bias+relu+W2-dot; svs = dinv*result.
__global__ __launch_bounds__(256) void k_agg_mlp(const uint4* __restrict__ Xs4,
                                                 const int* __restrict__ rowPtr,
                                                 const int* __restrict__ eSrc,
                                                 const float* __restrict__ dinv,
                                                 const uint4* __restrict__ W1t4,
                                                 const float* __restrict__ b1,
                                                 const float* __restrict__ W2,
                                                 float* __restrict__ svs, int n) {
    __shared__ __align__(16) unsigned short W1s[HID * INF];  // 16 KB swizzled
    __shared__ __align__(16) unsigned short aggS[32 * INF];  // 4 KB swizzled
    __shared__ float b1s[HID];
    __shared__ float W2s[HID];
    int tid = threadIdx.x;

    // phase 0: stage W1t into swizzled LDS (+ bias/W2)
    for (int i = tid; i < HID * 8; i += 256) {   // 1024 uint4 chunks
        int c = i >> 3, cb = i & 7;
        uint4 v = W1t4[i];
        int off = c * 128 + ((cb * 16) ^ ((c & 7) << 4));
        *(uint4*)((char*)W1s + off) = v;
    }
    if (tid < HID) {
        b1s[tid] = b1[tid];
        W2s[tid] = W2[tid];
    }

    // phase 1: gather
    int node0 = blockIdx.x * 32;
    int w = tid >> 3;   // local node 0..31
    int r = tid & 7;    // 16B chunk of the 128B row
    int node = node0 + w;
    if (node < n) {
        int beg = rowPtr[node];
        int end = rowPtr[node + 1];
        float dD = dinv[node];
        float acc[8];
        {   // self-loop init
            uint4 v = Xs4[(size_t)node * 8 + r];
            const __half2* hp = (const __half2*)&v;
#pragma unroll
            for (int i = 0; i < 4; ++i) {
                float2 f = __half22float2(hp[i]);
                acc[2 * i] = f.x;
                acc[2 * i + 1] = f.y;
            }
        }
        int j = beg;
        int aEnd = min(end, (beg + 3) & ~3);
        for (; j < aEnd; ++j) {
            uint4 v = Xs4[(size_t)eSrc[j] * 8 + r];
            acc8_add(v, acc);
        }
        for (; j + 3 < end; j += 4) {
            int4 s4 = *(const int4*)(eSrc + j);
            uint4 v0 = Xs4[(size_t)s4.x * 8 + r];
            uint4 v1 = Xs4[(size_t)s4.y * 8 + r];
            uint4 v2 = Xs4[(size_t)s4.z * 8 + r];
            uint4 v3 = Xs4[(size_t)s4.w * 8 + r];
            acc8_add(v0, acc); acc8_add(v1, acc); acc8_add(v2, acc); acc8_add(v3, acc);
        }
        for (; j < end; ++j) {
            uint4 v = Xs4[(size_t)eSrc[j] * 8 + r];
            acc8_add(v, acc);
        }
        __half2 h0 = __float22half2_rn(make_float2(dD * acc[0], dD * acc[1]));
        __half2 h1 = __float22half2_rn(make_float2(dD * acc[2], dD * acc[3]));
        __half2 h2 = __float22half2_rn(make_float2(dD * acc[4], dD * acc[5]));
        __half2 h3 = __float22half2_rn(make_float2(dD * acc[6], dD * acc[7]));
        uint4 o;
        o.x = *(unsigned*)&h0; o.y = *(unsigned*)&h1;
        o.z = *(unsigned*)&h2; o.w = *(unsigned*)&h3;
        int off = w * 128 + ((r * 16) ^ ((w & 7) << 4));
        *(uint4*)((char*)aggS + off) = o;
    }
    __syncthreads();

    // phase 2: MFMA (waves 0-1)
    int wave = tid >> 6;
    if (wave < 2) {
        int l = tid & 63;
        int row16 = l & 15;
        int kg = l >> 4;
        int lrow = wave * 16 + row16;
        int swzA = (lrow & 7) << 4;
        half8 a0 = *(const half8*)((const char*)aggS + lrow * 128 + ((kg * 16) ^ swzA));
        half8 a1 = *(const half8*)((const char*)aggS + lrow * 128 + ((64 + kg * 16) ^ swzA));
        float p0 = 0.0f, p1 = 0.0f, p2 = 0.0f, p3 = 0.0f;
#pragma unroll
        for (int nt = 0; nt < 8; ++nt) {
            int c = nt * 16 + row16;
            int swzB = (c & 7) << 4;
            half8 bf0 = *(const half8*)((const char*)W1s + c * 128 + ((kg * 16) ^ swzB));
            half8 bf1 = *(const half8*)((const char*)W1s + c * 128 + ((64 + kg * 16) ^ swzB));
            f32x4 acc4 = {0.0f, 0.0f, 0.0f, 0.0f};
            acc4 = __builtin_amdgcn_mfma_f32_16x16x32_f16(a0, bf0, acc4, 0, 0, 0);
            acc4 = __builtin_amdgcn_mfma_f32_16x16x32_f16(a1, bf1, acc4, 0, 0, 0);
            float b1v = b1s[c];
            float w2v = W2s[c];
            float h;
            h = fmaxf(acc4[0] + b1v, 0.0f); p0 = fmaf(h, w2v, p0);
            h = fmaxf(acc4[1] + b1v, 0.0f); p1 = fmaf(h, w2v, p1);
            h = fmaxf(acc4[2] + b1v, 0.0f); p2 = fmaf(h, w2v, p2);
            h = fmaxf(acc4[3] + b1v, 0.0f); p3 = fmaf(h, w2v, p3);
        }
#pragma unroll
        for (int off = 1; off < 16; off <<= 1) {
            p0 += __shfl_xor(p0, off, 64);
            p1 += __shfl_xor(p1, off, 64);
            p2 += __shfl_xor(p2, off, 64);
            p3 += __shfl_xor(p3, off, 64);
        }
        if (row16 == 0) {
            int nd = node0 + wave * 16 + kg * 4;
            if (nd + 0 < n) svs[nd + 0] = dinv[nd + 0] * p0;
            if (nd + 1 < n) svs[nd + 1] = dinv[nd + 1] * p1;
            if (nd + 2 < n) svs[nd + 2] = dinv[nd + 2] * p2;
            if (nd + 3 < n) svs[nd + 3] = dinv[nd + 3] * p3;
        }
    }
}

// 4 nodes per wave: out[d] = dD*(sum svs[src] + svs[d]) + b2
__global__ __launch_bounds__(256) void k_out(const int* __restrict__ rowPtr,
                                             const int* __restrict__ eSrc,
                                             const float* __restrict__ dinv,
                                             const float* __restrict__ svs,
                                             const float* __restrict__ b2,
                                             float* __restrict__ out, int n) {
    int t = blockIdx.x * blockDim.x + threadIdx.x;
    int node = t >> 4;
    int r = t & 15;
    if (node >= n) return;
    int beg = rowPtr[node];
    int end = rowPtr[node + 1];
    float p = 0.0f;
    for (int j = beg + r; j < end; j += 16) p += svs[eSrc[j]];
    p += __shfl_xor(p, 1, 16);
    p += __shfl_xor(p, 2, 16);
    p += __shfl_xor(p, 4, 16);
    p += __shfl_xor(p, 8, 16);
    if (r == 0) {
        float dD = dinv[node];
        out[node] = fmaf(dD, p + svs[node], b2[0]);
    }
}

extern "C" void kernel_launch(void* const* d_in, const int* in_sizes, int n_in,
                              void* d_out, int out_size, void* d_ws, size_t ws_size,
                              hipStream_t stream) {
    const float* X  = (const float*)d_in[0];
    const int*   ei = (const int*)d_in[1];   // int32 (jax x64 disabled)
    const float* W1 = (const float*)d_in[2];
    const float* b1 = (const float*)d_in[3];
    const float* W2 = (const float*)d_in[4];
    const float* b2 = (const float*)d_in[5];

    int N = in_sizes[0] / INF;  // 100000
    int E = in_sizes[1] / 2;    // 1600000
    const int* srcA = ei;
    const int* dstA = ei + E;

    int nt  = (E + TILE_E - 1) / TILE_E;  // 98 tiles
    int nbk = (N + 1023) >> 10;           // 98 buckets

    // workspace layout (16B-aligned head first)
    uint4*    Xs4      = (uint4*)d_ws;                     // N*8 = 12.8 MB
    unsigned* binned   = (unsigned*)(Xs4 + (size_t)N * 8); // E
    int*      eSrc     = (int*)(binned + E);               // E
    _Float16* W1t      = (_Float16*)(eSrc + E);            // HID*INF = 16 KB
    int*      tileCnt  = (int*)(W1t + HID * INF);          // nt*MAXBK
    int*      tileBase = tileCnt + nt * MAXBK;             // nt*MAXBK
    int*      bBase    = tileBase + nt * MAXBK;            // nbk+1
    int*      rowPtr   = bBase + nbk + 1;                  // N+1
    float*    dinv     = (float*)(rowPtr + N + 1);         // N
    float*    svs      = dinv + N;                         // N
    float*    out      = (float*)d_out;

    k_thist<<<nt, 1024, 0, stream>>>(dstA, tileCnt, E);
    k_bscan<<<1, 1024, 0, stream>>>(tileCnt, tileBase, bBase, rowPtr, N, nbk, nt);
    k_bin<<<nt, 1024, 0, stream>>>(srcA, dstA, tileBase, binned, E);
    k_csr<<<nbk, 1024, 0, stream>>>(binned, bBase, rowPtr, dinv, eSrc, N);
    k_prescale<<<(N * 8 + HID * INF + 255) / 256, 256, 0, stream>>>(
        (const float4*)X, dinv, Xs4, W1, W1t, N);
    k_agg_mlp<<<(N + 31) / 32, 256, 0, stream>>>(Xs4, rowPtr, eSrc, dinv,
                                                 (const uint4*)W1t, b1, W2, svs, N);
    k_out<<<(N * 16 + 255) / 256, 256, 0, stream>>>(rowPtr, eSrc, dinv, svs, b2, out, N);
}